// Round 1
// baseline (1020.545 us; speedup 1.0000x reference)
//
#include <hip/hip_runtime.h>

// Problem constants (B,T,A,D,U) = (64, 2048, 512, 512, 512)
constexpr int U = 512;
constexpr int B = 64;
constexpr int T = 2048;
constexpr int A = 512;

typedef __attribute__((ext_vector_type(8))) short short8;   // 8 bf16 = 4 VGPRs (MFMA A/B frag)
typedef __attribute__((ext_vector_type(4))) float f32x4;    // MFMA C/D frag

__device__ __forceinline__ unsigned short f32_to_bf16(float f) {
    unsigned int b = __float_as_uint(f);
    unsigned int r = (b + 0x7FFFu + ((b >> 16) & 1u)) >> 16;
    return (unsigned short)r;
}

__device__ __forceinline__ float fast_tanh(float x) {
    // tanh(x) = (e^{2x}-1)/(e^{2x}+1), e^{2x} = exp2(x * 2*log2(e))
    float e = exp2f(x * 2.885390081777927f);
    return (e - 1.0f) * __builtin_amdgcn_rcpf(e + 1.0f);
}

__device__ __forceinline__ float hard_sigmoid(float z) {
    return fminf(fmaxf(0.2f * z + 0.5f, 0.0f), 1.0f);
}

// ---------------------------------------------------------------------------
// K1a: S[b][u] = bias_u[u] + sum_k h[b][k] * kernel_w[k][u]   (Wxstm + bias_u)
// grid 128 x 256
__global__ __launch_bounds__(256) void k_prep_s(const float* __restrict__ h,
                                                const float* __restrict__ kw,
                                                const float* __restrict__ bias,
                                                float* __restrict__ S) {
    int b = blockIdx.x >> 1;
    int u = ((blockIdx.x & 1) << 8) + threadIdx.x;
    const float* hb = h + b * U;
    float acc = bias[4 * U + u];
    for (int k = 0; k < U; ++k) acc += hb[k] * kw[k * U + u];
    S[b * U + u] = acc;
}

// ---------------------------------------------------------------------------
// K1b: kut[u][a] = bf16(kernel_u[a][u])   (transposed bf16 copy, 512 KB)
// grid 256 x 256  (16x16 tiles of 32x32)
__global__ __launch_bounds__(256) void k_prep_kut(const float* __restrict__ ku,
                                                  unsigned short* __restrict__ kut) {
    __shared__ float tile[32][33];
    int a0 = (blockIdx.x >> 4) << 5;
    int u0 = (blockIdx.x & 15) << 5;
    int c = threadIdx.x & 31, r0 = threadIdx.x >> 5;
#pragma unroll
    for (int p = 0; p < 4; ++p) {
        int r = r0 + p * 8;
        tile[r][c] = ku[(a0 + r) * U + u0 + c];
    }
    __syncthreads();
#pragma unroll
    for (int p = 0; p < 4; ++p) {
        int r = r0 + p * 8;
        kut[(u0 + r) * A + a0 + c] = f32_to_bf16(tile[c][r]);
    }
}

// ---------------------------------------------------------------------------
// K2: the big fused kernel.
//   uh = ann @ ku  (bf16 MFMA), then et[b][t] = sum_u tanh(uh + S[b][u]) * v[u]
// Block: 512 threads = 8 waves. Tile: M=64 rows (t), N=512 (all u, 64 per wave),
// K=512 in BK=64 chunks. A staged fp32->bf16 in LDS (pad +8), B-frags read
// directly from L2-resident bf16 ku^T. Epilogue: in-register tanh/dot(v),
// shuffle + LDS reduction -> et written once per row, no atomics.
// grid 2048 x 512
__global__ __launch_bounds__(512) void k_gemm_et(const float* __restrict__ ann,
                                                 const unsigned short* __restrict__ kut,
                                                 const float* __restrict__ S,
                                                 const float* __restrict__ v,
                                                 float* __restrict__ et) {
    __shared__ unsigned short As[64][72];   // 64 rows x BK=64, +8 pad (bank spread)
    __shared__ float red[8][64];

    const int tid = threadIdx.x;
    const int wave = tid >> 6;
    const int lane = tid & 63;
    const int lanelo = lane & 15;
    const int quad = lane >> 4;

    const int tileM = blockIdx.x;       // 0..2047
    const int b = tileM >> 5;           // t-tiles per batch: 2048/64 = 32
    const int t0 = (tileM & 31) << 6;
    const int nbase = wave << 6;        // this wave's u range [nbase, nbase+64)

    const float* annBase = ann + ((size_t)(b * T + t0)) * A;

    f32x4 acc[4][4];
#pragma unroll
    for (int i = 0; i < 4; ++i)
#pragma unroll
        for (int j = 0; j < 4; ++j) acc[i][j] = {0.f, 0.f, 0.f, 0.f};

    const unsigned short* bptr[4];
#pragma unroll
    for (int ni = 0; ni < 4; ++ni)
        bptr[ni] = kut + (size_t)(nbase + ni * 16 + lanelo) * A;

    for (int k0 = 0; k0 < A; k0 += 64) {
        // stage A tile: 64 rows x 64 k, fp32 -> bf16
#pragma unroll
        for (int p = 0; p < 2; ++p) {
            int idx = p * 512 + tid;          // 0..1023
            int row = idx >> 4;
            int c4 = (idx & 15) << 2;
            f32x4 val = *(const f32x4*)(annBase + (size_t)row * A + k0 + c4);
            ushort4 sv;
            sv.x = f32_to_bf16(val.x);
            sv.y = f32_to_bf16(val.y);
            sv.z = f32_to_bf16(val.z);
            sv.w = f32_to_bf16(val.w);
            *(ushort4*)&As[row][c4] = sv;
        }
        __syncthreads();
#pragma unroll
        for (int s = 0; s < 2; ++s) {
            short8 afrag[4];
#pragma unroll
            for (int mi = 0; mi < 4; ++mi)
                afrag[mi] = *(const short8*)&As[mi * 16 + lanelo][s * 32 + quad * 8];
#pragma unroll
            for (int ni = 0; ni < 4; ++ni) {
                short8 bfrag = *(const short8*)(bptr[ni] + k0 + s * 32 + quad * 8);
#pragma unroll
                for (int mi = 0; mi < 4; ++mi)
                    acc[mi][ni] = __builtin_amdgcn_mfma_f32_16x16x32_bf16(
                        afrag[mi], bfrag, acc[mi][ni], 0, 0, 0);
            }
        }
        __syncthreads();
    }

    // Epilogue. C/D layout: col = lane&15, row = quad*4 + reg (verified m89/m91).
    float rowacc[16];
#pragma unroll
    for (int i = 0; i < 16; ++i) rowacc[i] = 0.f;
#pragma unroll
    for (int ni = 0; ni < 4; ++ni) {
        int n = nbase + ni * 16 + lanelo;
        float sv = S[b * U + n];
        float vv = v[n];
#pragma unroll
        for (int mi = 0; mi < 4; ++mi)
#pragma unroll
            for (int r = 0; r < 4; ++r)
                rowacc[mi * 4 + r] += fast_tanh(acc[mi][ni][r] + sv) * vv;
    }
    // reduce across the 16 lanes (lane&15) that share each row
#pragma unroll
    for (int i = 0; i < 16; ++i) {
        rowacc[i] += __shfl_xor(rowacc[i], 1);
        rowacc[i] += __shfl_xor(rowacc[i], 2);
        rowacc[i] += __shfl_xor(rowacc[i], 4);
        rowacc[i] += __shfl_xor(rowacc[i], 8);
    }
    if (lanelo == 0) {
#pragma unroll
        for (int mi = 0; mi < 4; ++mi)
#pragma unroll
            for (int r = 0; r < 4; ++r)
                red[wave][mi * 16 + quad * 4 + r] = rowacc[mi * 4 + r];
    }
    __syncthreads();
    if (tid < 64) {
        float s = 0.f;
#pragma unroll
        for (int w = 0; w < 8; ++w) s += red[w][tid];
        et[b * T + t0 + tid] = s;
    }
}

// ---------------------------------------------------------------------------
// K3: softmax over T per batch. grid 64 x 256
__global__ __launch_bounds__(256) void k_softmax(const float* __restrict__ et,
                                                 float* __restrict__ at) {
    __shared__ float sred[256];
    int b = blockIdx.x;
    const float* e = et + b * T;
    float mx = -1e30f;
    for (int t = threadIdx.x; t < T; t += 256) mx = fmaxf(mx, e[t]);
    sred[threadIdx.x] = mx;
    __syncthreads();
    for (int s = 128; s > 0; s >>= 1) {
        if (threadIdx.x < s) sred[threadIdx.x] = fmaxf(sred[threadIdx.x], sred[threadIdx.x + s]);
        __syncthreads();
    }
    mx = sred[0];
    __syncthreads();
    float vals[8];
    float sum = 0.f;
#pragma unroll
    for (int i = 0; i < 8; ++i) {
        int t = threadIdx.x + i * 256;
        float x = exp2f((e[t] - mx) * 1.4426950408889634f);
        vals[i] = x;
        sum += x;
    }
    sred[threadIdx.x] = sum;
    __syncthreads();
    for (int s = 128; s > 0; s >>= 1) {
        if (threadIdx.x < s) sred[threadIdx.x] += sred[threadIdx.x + s];
        __syncthreads();
    }
    float inv = 1.0f / sred[0];
#pragma unroll
    for (int i = 0; i < 8; ++i) at[b * T + threadIdx.x + i * 256] = vals[i] * inv;
}

// ---------------------------------------------------------------------------
// K4: context partials: part[b][tc][a] = sum_{t in chunk} at[b][t]*ann[b][t][a]
// grid (64*16) x 256, t-chunks of 128. Memory-bound second pass over ann.
__global__ __launch_bounds__(256) void k_ctx_part(const float* __restrict__ at,
                                                  const float* __restrict__ ann,
                                                  float* __restrict__ part) {
    int b = blockIdx.x >> 4;
    int tc = blockIdx.x & 15;
    int a2 = threadIdx.x << 1;
    const float* annb = ann + ((size_t)b * T + tc * 128) * A;
    const float* atb = at + b * T + tc * 128;
    float acc0 = 0.f, acc1 = 0.f;
    for (int t = 0; t < 128; ++t) {
        float w = atb[t];
        float2 rv = *(const float2*)(annb + (size_t)t * A + a2);
        acc0 += w * rv.x;
        acc1 += w * rv.y;
    }
    float* p = part + ((size_t)b * 16 + tc) * A;
    p[a2] = acc0;
    p[a2 + 1] = acc1;
}

// ---------------------------------------------------------------------------
// K5: reduce partials -> context. grid 64 x 256
__global__ __launch_bounds__(256) void k_ctx_reduce(const float* __restrict__ part,
                                                    float* __restrict__ ctx) {
    int b = blockIdx.x;
    for (int a = threadIdx.x; a < A; a += 256) {
        float s = 0.f;
#pragma unroll
        for (int c = 0; c < 16; ++c) s += part[((size_t)b * 16 + c) * A + a];
        ctx[b * A + a] = s;
    }
}

// ---------------------------------------------------------------------------
// K6: z = [inputs, ctx] @ kernel + h @ rk + bias ; gates ; h_new.
// grid = 16 b-groups (btile=4) * 8 u-chunks = 128 blocks x 256 threads.
// thread = (gate g, u_local); 4 batches accumulated per thread; gate combine
// via LDS exchange.
__global__ __launch_bounds__(256) void k_zgate(const float* __restrict__ inputs,
                                               const float* __restrict__ ctx,
                                               const float* __restrict__ h,
                                               const float* __restrict__ c,
                                               const float* __restrict__ kern,
                                               const float* __restrict__ rk,
                                               const float* __restrict__ bias,
                                               float* __restrict__ hnew) {
    __shared__ float x[4][1536];        // [bi][ inputs(512) | ctx(512) | h(512) ]
    __shared__ float zb[4][4][64];      // [gate][bi][u_local]
    int bg = blockIdx.x >> 3;
    int uc = blockIdx.x & 7;
    int b0 = bg << 2;
    for (int idx = threadIdx.x; idx < 4 * 1536; idx += 256) {
        int bi = idx / 1536, k = idx - bi * 1536;
        float val;
        if (k < 512) val = inputs[(b0 + bi) * 512 + k];
        else if (k < 1024) val = ctx[(b0 + bi) * 512 + (k - 512)];
        else val = h[(b0 + bi) * 512 + (k - 1024)];
        x[bi][k] = val;
    }
    __syncthreads();

    int ul = threadIdx.x & 63;
    int g = threadIdx.x >> 6;
    int u = (uc << 6) + ul;
    int j = (g << 9) + u;
    float bj = bias[j];
    float a0 = bj, a1 = bj, a2 = bj, a3 = bj;
    for (int k = 0; k < 1024; ++k) {
        float w = kern[k * 2048 + j];
        a0 += x[0][k] * w;
        a1 += x[1][k] * w;
        a2 += x[2][k] * w;
        a3 += x[3][k] * w;
    }
    for (int k = 0; k < 512; ++k) {
        float w = rk[k * 2048 + j];
        a0 += x[0][1024 + k] * w;
        a1 += x[1][1024 + k] * w;
        a2 += x[2][1024 + k] * w;
        a3 += x[3][1024 + k] * w;
    }
    zb[g][0][ul] = a0;
    zb[g][1][ul] = a1;
    zb[g][2][ul] = a2;
    zb[g][3][ul] = a3;
    __syncthreads();

    int bi = threadIdx.x >> 6;          // reuse all 256 threads: (bi, ul)
    int bb = b0 + bi;
    int uu = (uc << 6) + ul;
    float zi = zb[0][bi][ul];
    float zf = zb[1][bi][ul];
    float zc = zb[2][bi][ul];
    float zo = zb[3][bi][ul];
    float ig = hard_sigmoid(zi);
    float fg = hard_sigmoid(zf);
    float cn = fg * c[bb * 512 + uu] + ig * fast_tanh(zc);
    float og = hard_sigmoid(zo);
    hnew[bb * 512 + uu] = og * fast_tanh(cn);
}

// ---------------------------------------------------------------------------
extern "C" void kernel_launch(void* const* d_in, const int* in_sizes, int n_in,
                              void* d_out, int out_size, void* d_ws, size_t ws_size,
                              hipStream_t stream) {
    const float* inputs = (const float*)d_in[0];
    const float* h      = (const float*)d_in[1];
    const float* c      = (const float*)d_in[2];
    const float* ann    = (const float*)d_in[3];
    const float* kern   = (const float*)d_in[4];
    const float* rk     = (const float*)d_in[5];
    const float* bias   = (const float*)d_in[6];
    const float* ku     = (const float*)d_in[7];
    const float* kw     = (const float*)d_in[8];
    const float* kv     = (const float*)d_in[9];

    // ws layout (bytes): S 128K | kut(bf16) 512K | et 512K | at 512K | part 2M | ctx 128K
    char* ws = (char*)d_ws;
    float*          S    = (float*)(ws + 0);
    unsigned short* kut  = (unsigned short*)(ws + 131072);
    float*          et   = (float*)(ws + 655360);
    float*          at   = (float*)(ws + 1179648);
    float*          part = (float*)(ws + 1703936);
    float*          ctx  = (float*)(ws + 3801088);
    float*          hnew = (float*)d_out;

    k_prep_s<<<128, 256, 0, stream>>>(h, kw, bias, S);
    k_prep_kut<<<256, 256, 0, stream>>>(ku, kut);
    k_gemm_et<<<2048, 512, 0, stream>>>(ann, kut, S, kv, et);
    k_softmax<<<64, 256, 0, stream>>>(et, at);
    k_ctx_part<<<64 * 16, 256, 0, stream>>>(at, ann, part);
    k_ctx_reduce<<<64, 256, 0, stream>>>(part, ctx);
    k_zgate<<<128, 256, 0, stream>>>(inputs, ctx, h, c, kern, rk, bias, hnew);
}

// Round 2
// 606.317 us; speedup vs baseline: 1.6832x; 1.6832x over previous
//
#include <hip/hip_runtime.h>

// Problem constants (B,T,A,D,U) = (64, 2048, 512, 512, 512)
constexpr int U = 512;
constexpr int B = 64;
constexpr int T = 2048;
constexpr int A = 512;

typedef __attribute__((ext_vector_type(8))) short short8;   // 8 bf16 = 4 VGPRs (MFMA A/B frag)
typedef __attribute__((ext_vector_type(4))) float f32x4;    // MFMA C/D frag

__device__ __forceinline__ unsigned short f32_to_bf16(float f) {
    unsigned int b = __float_as_uint(f);
    unsigned int r = (b + 0x7FFFu + ((b >> 16) & 1u)) >> 16;
    return (unsigned short)r;
}

__device__ __forceinline__ float fast_tanh(float x) {
    float e = exp2f(x * 2.885390081777927f);
    return (e - 1.0f) * __builtin_amdgcn_rcpf(e + 1.0f);
}

__device__ __forceinline__ float hard_sigmoid(float z) {
    return fminf(fmaxf(0.2f * z + 0.5f, 0.0f), 1.0f);
}

// ---------------------------------------------------------------------------
// K1a: S[b][u] = bias_u[u] + sum_k h[b][k] * kernel_w[k][u]   (Wxstm + bias_u)
// grid 128 x 256
__global__ __launch_bounds__(256) void k_prep_s(const float* __restrict__ h,
                                                const float* __restrict__ kw,
                                                const float* __restrict__ bias,
                                                float* __restrict__ S) {
    int b = blockIdx.x >> 1;
    int u = ((blockIdx.x & 1) << 8) + threadIdx.x;
    const float* hb = h + b * U;
    float acc = bias[4 * U + u];
    for (int k = 0; k < U; ++k) acc += hb[k] * kw[k * U + u];
    S[b * U + u] = acc;
}

// ---------------------------------------------------------------------------
// K1b: kut[u][a] = bf16(kernel_u[a][u])   (transposed bf16 copy, 512 KB)
// grid 256 x 256  (16x16 tiles of 32x32)
__global__ __launch_bounds__(256) void k_prep_kut(const float* __restrict__ ku,
                                                  unsigned short* __restrict__ kut) {
    __shared__ float tile[32][33];
    int a0 = (blockIdx.x >> 4) << 5;
    int u0 = (blockIdx.x & 15) << 5;
    int c = threadIdx.x & 31, r0 = threadIdx.x >> 5;
#pragma unroll
    for (int p = 0; p < 4; ++p) {
        int r = r0 + p * 8;
        tile[r][c] = ku[(a0 + r) * U + u0 + c];
    }
    __syncthreads();
#pragma unroll
    for (int p = 0; p < 4; ++p) {
        int r = r0 + p * 8;
        kut[(u0 + r) * A + a0 + c] = f32_to_bf16(tile[c][r]);
    }
}

// ---------------------------------------------------------------------------
// K1c: Wt[j][k] = bf16( W[k][j] ), W = [kernel (1024 rows); recurrent (512 rows)],
// j in [0,2048), k in [0,1536). grid (48, 64) x 256; 32x32 tiles via LDS.
__global__ __launch_bounds__(256) void k_prep_wt(const float* __restrict__ kern,
                                                 const float* __restrict__ rk,
                                                 unsigned short* __restrict__ Wt) {
    __shared__ float tile[32][33];
    int kt = blockIdx.x;            // 0..47  (k tile)
    int jt = blockIdx.y;            // 0..63  (j tile)
    int k0 = kt << 5;
    int j0 = jt << 5;
    int c = threadIdx.x & 31, r0 = threadIdx.x >> 5;
#pragma unroll
    for (int p = 0; p < 4; ++p) {
        int r = r0 + p * 8;
        int k = k0 + r;
        float val = (k < 1024) ? kern[k * 2048 + j0 + c]
                               : rk[(k - 1024) * 2048 + j0 + c];
        tile[r][c] = val;
    }
    __syncthreads();
#pragma unroll
    for (int p = 0; p < 4; ++p) {
        int r = r0 + p * 8;
        Wt[(size_t)(j0 + r) * 1536 + k0 + c] = f32_to_bf16(tile[c][r]);
    }
}

// ---------------------------------------------------------------------------
// K2: the big fused kernel.
//   uh = ann @ ku  (bf16 MFMA), then et[b][t] = sum_u tanh(uh + S[b][u]) * v[u]
// grid 2048 x 512
__global__ __launch_bounds__(512) void k_gemm_et(const float* __restrict__ ann,
                                                 const unsigned short* __restrict__ kut,
                                                 const float* __restrict__ S,
                                                 const float* __restrict__ v,
                                                 float* __restrict__ et) {
    __shared__ unsigned short As[64][72];   // 64 rows x BK=64, +8 pad
    __shared__ float red[8][64];

    const int tid = threadIdx.x;
    const int wave = tid >> 6;
    const int lane = tid & 63;
    const int lanelo = lane & 15;
    const int quad = lane >> 4;

    const int tileM = blockIdx.x;       // 0..2047
    const int b = tileM >> 5;           // 2048/64 = 32 t-tiles per batch
    const int t0 = (tileM & 31) << 6;
    const int nbase = wave << 6;

    const float* annBase = ann + ((size_t)(b * T + t0)) * A;

    f32x4 acc[4][4];
#pragma unroll
    for (int i = 0; i < 4; ++i)
#pragma unroll
        for (int j = 0; j < 4; ++j) acc[i][j] = {0.f, 0.f, 0.f, 0.f};

    const unsigned short* bptr[4];
#pragma unroll
    for (int ni = 0; ni < 4; ++ni)
        bptr[ni] = kut + (size_t)(nbase + ni * 16 + lanelo) * A;

    for (int k0 = 0; k0 < A; k0 += 64) {
#pragma unroll
        for (int p = 0; p < 2; ++p) {
            int idx = p * 512 + tid;
            int row = idx >> 4;
            int c4 = (idx & 15) << 2;
            f32x4 val = *(const f32x4*)(annBase + (size_t)row * A + k0 + c4);
            ushort4 sv;
            sv.x = f32_to_bf16(val.x);
            sv.y = f32_to_bf16(val.y);
            sv.z = f32_to_bf16(val.z);
            sv.w = f32_to_bf16(val.w);
            *(ushort4*)&As[row][c4] = sv;
        }
        __syncthreads();
#pragma unroll
        for (int s = 0; s < 2; ++s) {
            short8 afrag[4];
#pragma unroll
            for (int mi = 0; mi < 4; ++mi)
                afrag[mi] = *(const short8*)&As[mi * 16 + lanelo][s * 32 + quad * 8];
#pragma unroll
            for (int ni = 0; ni < 4; ++ni) {
                short8 bfrag = *(const short8*)(bptr[ni] + k0 + s * 32 + quad * 8);
#pragma unroll
                for (int mi = 0; mi < 4; ++mi)
                    acc[mi][ni] = __builtin_amdgcn_mfma_f32_16x16x32_bf16(
                        afrag[mi], bfrag, acc[mi][ni], 0, 0, 0);
            }
        }
        __syncthreads();
    }

    float rowacc[16];
#pragma unroll
    for (int i = 0; i < 16; ++i) rowacc[i] = 0.f;
#pragma unroll
    for (int ni = 0; ni < 4; ++ni) {
        int n = nbase + ni * 16 + lanelo;
        float sv = S[b * U + n];
        float vv = v[n];
#pragma unroll
        for (int mi = 0; mi < 4; ++mi)
#pragma unroll
            for (int r = 0; r < 4; ++r)
                rowacc[mi * 4 + r] += fast_tanh(acc[mi][ni][r] + sv) * vv;
    }
#pragma unroll
    for (int i = 0; i < 16; ++i) {
        rowacc[i] += __shfl_xor(rowacc[i], 1);
        rowacc[i] += __shfl_xor(rowacc[i], 2);
        rowacc[i] += __shfl_xor(rowacc[i], 4);
        rowacc[i] += __shfl_xor(rowacc[i], 8);
    }
    if (lanelo == 0) {
#pragma unroll
        for (int mi = 0; mi < 4; ++mi)
#pragma unroll
            for (int r = 0; r < 4; ++r)
                red[wave][mi * 16 + quad * 4 + r] = rowacc[mi * 4 + r];
    }
    __syncthreads();
    if (tid < 64) {
        float s = 0.f;
#pragma unroll
        for (int w = 0; w < 8; ++w) s += red[w][tid];
        et[b * T + t0 + tid] = s;
    }
}

// ---------------------------------------------------------------------------
// K3: softmax over T per batch. grid 64 x 256
__global__ __launch_bounds__(256) void k_softmax(const float* __restrict__ et,
                                                 float* __restrict__ at) {
    __shared__ float sred[256];
    int b = blockIdx.x;
    const float* e = et + b * T;
    float mx = -1e30f;
    for (int t = threadIdx.x; t < T; t += 256) mx = fmaxf(mx, e[t]);
    sred[threadIdx.x] = mx;
    __syncthreads();
    for (int s = 128; s > 0; s >>= 1) {
        if (threadIdx.x < s) sred[threadIdx.x] = fmaxf(sred[threadIdx.x], sred[threadIdx.x + s]);
        __syncthreads();
    }
    mx = sred[0];
    __syncthreads();
    float vals[8];
    float sum = 0.f;
#pragma unroll
    for (int i = 0; i < 8; ++i) {
        int t = threadIdx.x + i * 256;
        float x = exp2f((e[t] - mx) * 1.4426950408889634f);
        vals[i] = x;
        sum += x;
    }
    sred[threadIdx.x] = sum;
    __syncthreads();
    for (int s = 128; s > 0; s >>= 1) {
        if (threadIdx.x < s) sred[threadIdx.x] += sred[threadIdx.x + s];
        __syncthreads();
    }
    float inv = 1.0f / sred[0];
#pragma unroll
    for (int i = 0; i < 8; ++i) at[b * T + threadIdx.x + i * 256] = vals[i] * inv;
}

// ---------------------------------------------------------------------------
// K4: context partials. grid (64*16) x 256
__global__ __launch_bounds__(256) void k_ctx_part(const float* __restrict__ at,
                                                  const float* __restrict__ ann,
                                                  float* __restrict__ part) {
    int b = blockIdx.x >> 4;
    int tc = blockIdx.x & 15;
    int a2 = threadIdx.x << 1;
    const float* annb = ann + ((size_t)b * T + tc * 128) * A;
    const float* atb = at + b * T + tc * 128;
    float acc0 = 0.f, acc1 = 0.f;
    for (int t = 0; t < 128; ++t) {
        float w = atb[t];
        float2 rv = *(const float2*)(annb + (size_t)t * A + a2);
        acc0 += w * rv.x;
        acc1 += w * rv.y;
    }
    float* p = part + ((size_t)b * 16 + tc) * A;
    p[a2] = acc0;
    p[a2 + 1] = acc1;
}

// ---------------------------------------------------------------------------
// K5: reduce partials -> context. grid 64 x 256
__global__ __launch_bounds__(256) void k_ctx_reduce(const float* __restrict__ part,
                                                    float* __restrict__ ctx) {
    int b = blockIdx.x;
    for (int a = threadIdx.x; a < A; a += 256) {
        float s = 0.f;
#pragma unroll
        for (int c = 0; c < 16; ++c) s += part[((size_t)b * 16 + c) * A + a];
        ctx[b * A + a] = s;
    }
}

// ---------------------------------------------------------------------------
// K5b: xb[b][0:1536] = bf16([inputs | ctx | h]). grid (6, 64) x 256
__global__ __launch_bounds__(256) void k_prep_xb(const float* __restrict__ inputs,
                                                 const float* __restrict__ ctx,
                                                 const float* __restrict__ h,
                                                 unsigned short* __restrict__ xb) {
    int b = blockIdx.y;
    int k = blockIdx.x * 256 + threadIdx.x;     // 0..1535, block-uniform segment
    float val;
    if (k < 512) val = inputs[b * 512 + k];
    else if (k < 1024) val = ctx[b * 512 + (k - 512)];
    else val = h[b * 512 + (k - 1024)];
    xb[b * 1536 + k] = f32_to_bf16(val);
}

// ---------------------------------------------------------------------------
// K6a: z-GEMM, split-K MFMA. z = xb(64x1536) @ Wt^T(1536x2048), partials per
// k-chunk. grid 256 blocks (32 n-tiles x 8 k-chunks of 192) x 256 threads
// (4 waves; wave w covers n-range [nt*64+w*16, +16)). A and B frags are
// direct 16B global loads (xb L2-resident; each Wt element read exactly once
// grid-wide). No LDS, no barriers, deterministic fp32 partials.
__global__ __launch_bounds__(256) void k_zgemm(const unsigned short* __restrict__ xb,
                                               const unsigned short* __restrict__ Wt,
                                               float* __restrict__ zpart) {
    const int kc = blockIdx.x & 7;      // k-chunk: 192 wide
    const int nt = blockIdx.x >> 3;     // 0..31
    const int wave = threadIdx.x >> 6;
    const int lane = threadIdx.x & 63;
    const int lanelo = lane & 15;
    const int quad = lane >> 4;

    const int n = nt * 64 + wave * 16 + lanelo;
    const unsigned short* bp = Wt + (size_t)n * 1536 + kc * 192 + quad * 8;
    const unsigned short* ap = xb + (size_t)lanelo * 1536 + kc * 192 + quad * 8;

    f32x4 acc[4];
#pragma unroll
    for (int i = 0; i < 4; ++i) acc[i] = {0.f, 0.f, 0.f, 0.f};

#pragma unroll
    for (int ks = 0; ks < 6; ++ks) {
        short8 bfrag = *(const short8*)(bp + ks * 32);
#pragma unroll
        for (int mi = 0; mi < 4; ++mi) {
            short8 afrag = *(const short8*)(ap + (size_t)mi * 16 * 1536 + ks * 32);
            acc[mi] = __builtin_amdgcn_mfma_f32_16x16x32_bf16(afrag, bfrag, acc[mi], 0, 0, 0);
        }
    }

    // C/D layout: col = lane&15 (n), row = quad*4 + r (m)
    float* p = zpart + (size_t)kc * 64 * 2048;
#pragma unroll
    for (int mi = 0; mi < 4; ++mi)
#pragma unroll
        for (int r = 0; r < 4; ++r) {
            int m = mi * 16 + quad * 4 + r;
            p[(size_t)m * 2048 + n] = acc[mi][r];
        }
}

// ---------------------------------------------------------------------------
// K6b: combine partials + bias -> gates -> h_new. grid 128 x 256
__global__ __launch_bounds__(256) void k_gates(const float* __restrict__ zpart,
                                               const float* __restrict__ bias,
                                               const float* __restrict__ c,
                                               float* __restrict__ hnew) {
    int gid = blockIdx.x * 256 + threadIdx.x;   // 0..32767
    int b = gid >> 9;
    int u = gid & 511;
    float z[4];
#pragma unroll
    for (int g = 0; g < 4; ++g) {
        int j = (g << 9) + u;
        float s = bias[j];
#pragma unroll
        for (int kc = 0; kc < 8; ++kc)
            s += zpart[((size_t)kc * 64 + b) * 2048 + j];
        z[g] = s;
    }
    float ig = hard_sigmoid(z[0]);
    float fg = hard_sigmoid(z[1]);
    float cn = fg * c[b * 512 + u] + ig * fast_tanh(z[2]);
    float og = hard_sigmoid(z[3]);
    hnew[b * 512 + u] = og * fast_tanh(cn);
}

// ---------------------------------------------------------------------------
extern "C" void kernel_launch(void* const* d_in, const int* in_sizes, int n_in,
                              void* d_out, int out_size, void* d_ws, size_t ws_size,
                              hipStream_t stream) {
    const float* inputs = (const float*)d_in[0];
    const float* h      = (const float*)d_in[1];
    const float* c      = (const float*)d_in[2];
    const float* ann    = (const float*)d_in[3];
    const float* kern   = (const float*)d_in[4];
    const float* rk     = (const float*)d_in[5];
    const float* bias   = (const float*)d_in[6];
    const float* ku     = (const float*)d_in[7];
    const float* kw     = (const float*)d_in[8];
    const float* kv     = (const float*)d_in[9];

    // ws layout (bytes):
    //   S      @ 0         131072
    //   kut    @ 131072    524288
    //   et     @ 655360    524288
    //   at     @ 1179648   524288
    //   part   @ 1703936   2097152   (ctx partials)
    //   ctx    @ 3801088   131072
    //   xb     @ 3932160   196608    (bf16 [inputs|ctx|h])
    //   Wt     @ 4128768   6291456   (bf16 W^T, 2048x1536)
    //   zpart  @ 10420224  4194304   (8 x 64 x 2048 fp32)
    char* ws = (char*)d_ws;
    float*          S     = (float*)(ws + 0);
    unsigned short* kut   = (unsigned short*)(ws + 131072);
    float*          et    = (float*)(ws + 655360);
    float*          at    = (float*)(ws + 1179648);
    float*          part  = (float*)(ws + 1703936);
    float*          ctx   = (float*)(ws + 3801088);
    unsigned short* xb    = (unsigned short*)(ws + 3932160);
    unsigned short* Wt    = (unsigned short*)(ws + 4128768);
    float*          zpart = (float*)(ws + 10420224);
    float*          hnew  = (float*)d_out;

    k_prep_wt<<<dim3(48, 64), 256, 0, stream>>>(kern, rk, Wt);
    k_prep_s<<<128, 256, 0, stream>>>(h, kw, bias, S);
    k_prep_kut<<<256, 256, 0, stream>>>(ku, kut);
    k_gemm_et<<<2048, 512, 0, stream>>>(ann, kut, S, kv, et);
    k_softmax<<<64, 256, 0, stream>>>(et, at);
    k_ctx_part<<<64 * 16, 256, 0, stream>>>(at, ann, part);
    k_ctx_reduce<<<64, 256, 0, stream>>>(part, ctx);
    k_prep_xb<<<dim3(6, 64), 256, 0, stream>>>(inputs, ctx, h, xb);
    k_zgemm<<<256, 256, 0, stream>>>(xb, Wt, zpart);
    k_gates<<<128, 256, 0, stream>>>(zpart, bias, c, hnew);
}

// Round 3
// 557.444 us; speedup vs baseline: 1.8308x; 1.0877x over previous
//
#include <hip/hip_runtime.h>

// Problem constants (B,T,A,D,U) = (64, 2048, 512, 512, 512)
constexpr int U = 512;
constexpr int B = 64;
constexpr int T = 2048;
constexpr int A = 512;

typedef __attribute__((ext_vector_type(8))) short short8;   // 8 bf16 = 4 VGPRs (MFMA A/B frag)
typedef __attribute__((ext_vector_type(4))) float f32x4;    // MFMA C/D frag

__device__ __forceinline__ unsigned short f32_to_bf16(float f) {
    unsigned int b = __float_as_uint(f);
    unsigned int r = (b + 0x7FFFu + ((b >> 16) & 1u)) >> 16;
    return (unsigned short)r;
}

__device__ __forceinline__ float fast_tanh(float x) {
    float e = exp2f(x * 2.885390081777927f);
    return (e - 1.0f) * __builtin_amdgcn_rcpf(e + 1.0f);
}

__device__ __forceinline__ float hard_sigmoid(float z) {
    return fminf(fmaxf(0.2f * z + 0.5f, 0.0f), 1.0f);
}

// ---------------------------------------------------------------------------
// K1a: split-K partials for S = bias_u + h @ kernel_w.
// Sp[kc][b][u], kc in [0,4): sums k in [kc*128, +128). grid 256 x 256.
__global__ __launch_bounds__(256) void k_prep_s(const float* __restrict__ h,
                                                const float* __restrict__ kw,
                                                float* __restrict__ Sp) {
    int b = blockIdx.x >> 2;
    int kc = blockIdx.x & 3;
    int u = threadIdx.x;
    const float* hb = h + b * U + kc * 128;
    const float* kwb = kw + (size_t)kc * 128 * U;
    float a0 = 0.f, a1 = 0.f;
#pragma unroll 4
    for (int k = 0; k < 128; ++k) {
        float hv = hb[k];
        a0 += hv * kwb[(size_t)k * U + u];
        a1 += hv * kwb[(size_t)k * U + u + 256];
    }
    float* p = Sp + ((size_t)kc * 64 + b) * U;
    p[u] = a0;
    p[u + 256] = a1;
}

// K1a2: S[b][u] = bias_u[u] + sum_kc Sp. grid 128 x 256
__global__ __launch_bounds__(256) void k_s_reduce(const float* __restrict__ Sp,
                                                  const float* __restrict__ bias,
                                                  float* __restrict__ S) {
    int gid = blockIdx.x * 256 + threadIdx.x;   // 0..32767
    int b = gid >> 9, u = gid & 511;
    float s = bias[4 * U + u];
#pragma unroll
    for (int kc = 0; kc < 4; ++kc) s += Sp[((size_t)kc * 64 + b) * U + u];
    S[gid] = s;
}

// ---------------------------------------------------------------------------
// K1b: kut[u][a] = bf16(kernel_u[a][u])   (transposed bf16 copy, 512 KB)
// grid 256 x 256  (16x16 tiles of 32x32)
__global__ __launch_bounds__(256) void k_prep_kut(const float* __restrict__ ku,
                                                  unsigned short* __restrict__ kut) {
    __shared__ float tile[32][33];
    int a0 = (blockIdx.x >> 4) << 5;
    int u0 = (blockIdx.x & 15) << 5;
    int c = threadIdx.x & 31, r0 = threadIdx.x >> 5;
#pragma unroll
    for (int p = 0; p < 4; ++p) {
        int r = r0 + p * 8;
        tile[r][c] = ku[(a0 + r) * U + u0 + c];
    }
    __syncthreads();
#pragma unroll
    for (int p = 0; p < 4; ++p) {
        int r = r0 + p * 8;
        kut[(u0 + r) * A + a0 + c] = f32_to_bf16(tile[c][r]);
    }
}

// ---------------------------------------------------------------------------
// K1c: Wt[j][k] = bf16( W[k][j] ), W = [kernel (1024); recurrent (512)].
// grid (48, 64) x 256
__global__ __launch_bounds__(256) void k_prep_wt(const float* __restrict__ kern,
                                                 const float* __restrict__ rk,
                                                 unsigned short* __restrict__ Wt) {
    __shared__ float tile[32][33];
    int k0 = blockIdx.x << 5;
    int j0 = blockIdx.y << 5;
    int c = threadIdx.x & 31, r0 = threadIdx.x >> 5;
#pragma unroll
    for (int p = 0; p < 4; ++p) {
        int r = r0 + p * 8;
        int k = k0 + r;
        float val = (k < 1024) ? kern[k * 2048 + j0 + c]
                               : rk[(k - 1024) * 2048 + j0 + c];
        tile[r][c] = val;
    }
    __syncthreads();
#pragma unroll
    for (int p = 0; p < 4; ++p) {
        int r = r0 + p * 8;
        Wt[(size_t)(j0 + r) * 1536 + k0 + c] = f32_to_bf16(tile[c][r]);
    }
}

// ---------------------------------------------------------------------------
// K2: m97-style 128x128 MFMA GEMM + fused tanh/dot(v) epilogue.
//   uh = ann @ ku (bf16), etp[nt][m] = sum_{u in nt-tile} tanh(uh+S)*v[u]
// Block 256 thr = 4 waves (wm,wn in 2x2, 64x64 each). BK=64, K=512.
// A: fp32 global -> reg bf16 -> ds_write_b128 into padded As (stride 88 shorts,
//    rows 16B-aligned, bank-minimal). B: global_load_lds width=16 from bf16 kut
//    into unpadded Bs with XOR chunk swizzle (2-way banks = free).
// grid 4096 (mt 0..1023 x nt 0..3) x 256.
__global__ __launch_bounds__(256) void k_gemm_et(const float* __restrict__ ann,
                                                 const unsigned short* __restrict__ kut,
                                                 const float* __restrict__ S,
                                                 const float* __restrict__ v,
                                                 float* __restrict__ etp) {
    __shared__ unsigned short As[128 * 88];   // 128 rows x (64 data + 24 pad)
    __shared__ unsigned short Bs[128 * 64];   // unpadded (gll target), swizzled
    __shared__ float red[4][64];

    const int tid = threadIdx.x;
    const int wave = tid >> 6;
    const int lane = tid & 63;
    const int lanelo = lane & 15;
    const int quad = lane >> 4;
    const int wm = wave >> 1, wn = wave & 1;

    const int mt = blockIdx.x >> 2;      // 0..1023
    const int nt = blockIdx.x & 3;       // 0..3
    const int b = mt >> 4;               // 16 m-tiles per batch
    const float* aBase = ann + (size_t)mt * 128 * A;
    const unsigned short* bBase = kut + (size_t)nt * 128 * A;

    f32x4 acc[4][4];
#pragma unroll
    for (int i = 0; i < 4; ++i)
#pragma unroll
        for (int j = 0; j < 4; ++j) acc[i][j] = {0.f, 0.f, 0.f, 0.f};

    for (int k0 = 0; k0 < A; k0 += 64) {
        // --- B staging: async global->LDS, 16B/lane, 4 issues/wave ---
#pragma unroll
        for (int p = 0; p < 4; ++p) {
            int flat = p * 4096 + wave * 1024 + lane * 16;   // byte offset in Bs
            int nl = flat >> 7;                              // B row (n-local)
            int d = ((flat >> 4) & 7) ^ (nl & 7);            // swizzled data chunk
            __builtin_amdgcn_global_load_lds(
                (const __attribute__((address_space(1))) void*)(bBase + (size_t)nl * A + k0 + d * 8),
                (__attribute__((address_space(3))) void*)((char*)Bs + p * 4096 + wave * 1024),
                16, 0, 0);
        }
        // --- A staging: fp32 load, convert, 16B LDS store ---
#pragma unroll
        for (int p = 0; p < 4; ++p) {
            int flat8 = p * 256 + tid;         // 8-float chunk id (0..1023)
            int row = flat8 >> 3;
            int c8 = flat8 & 7;
            const float* src = aBase + (size_t)row * A + k0 + c8 * 8;
            f32x4 v0 = *(const f32x4*)src;
            f32x4 v1 = *(const f32x4*)(src + 4);
            short8 pk;
            pk[0] = (short)f32_to_bf16(v0.x);
            pk[1] = (short)f32_to_bf16(v0.y);
            pk[2] = (short)f32_to_bf16(v0.z);
            pk[3] = (short)f32_to_bf16(v0.w);
            pk[4] = (short)f32_to_bf16(v1.x);
            pk[5] = (short)f32_to_bf16(v1.y);
            pk[6] = (short)f32_to_bf16(v1.z);
            pk[7] = (short)f32_to_bf16(v1.w);
            *(short8*)&As[row * 88 + c8 * 8] = pk;
        }
        __syncthreads();
        // --- inner: 2 K=32 steps, 32 MFMA/wave ---
#pragma unroll
        for (int s = 0; s < 2; ++s) {
            short8 af[4], bfr[4];
#pragma unroll
            for (int mi = 0; mi < 4; ++mi) {
                int row = wm * 64 + mi * 16 + lanelo;
                af[mi] = *(const short8*)&As[row * 88 + s * 32 + quad * 8];
            }
#pragma unroll
            for (int ni = 0; ni < 4; ++ni) {
                int nl = wn * 64 + ni * 16 + lanelo;
                int ch = (s * 4 + quad) ^ (nl & 7);
                bfr[ni] = *(const short8*)&Bs[nl * 64 + ch * 8];
            }
#pragma unroll
            for (int mi = 0; mi < 4; ++mi)
#pragma unroll
                for (int ni = 0; ni < 4; ++ni)
                    acc[mi][ni] = __builtin_amdgcn_mfma_f32_16x16x32_bf16(
                        af[mi], bfr[ni], acc[mi][ni], 0, 0, 0);
        }
        __syncthreads();
    }

    // Epilogue. C/D: col(n) = lane&15, row(m) = quad*4 + r (verified m89/m91).
    float rows[16];
#pragma unroll
    for (int i = 0; i < 16; ++i) rows[i] = 0.f;
#pragma unroll
    for (int ni = 0; ni < 4; ++ni) {
        int n = nt * 128 + wn * 64 + ni * 16 + lanelo;
        float sv = S[b * U + n];
        float vv = v[n];
#pragma unroll
        for (int mi = 0; mi < 4; ++mi)
#pragma unroll
            for (int r = 0; r < 4; ++r)
                rows[mi * 4 + r] += fast_tanh(acc[mi][ni][r] + sv) * vv;
    }
#pragma unroll
    for (int i = 0; i < 16; ++i) {
        rows[i] += __shfl_xor(rows[i], 1);
        rows[i] += __shfl_xor(rows[i], 2);
        rows[i] += __shfl_xor(rows[i], 4);
        rows[i] += __shfl_xor(rows[i], 8);
    }
    if (lanelo == 0) {
#pragma unroll
        for (int mi = 0; mi < 4; ++mi)
#pragma unroll
            for (int r = 0; r < 4; ++r)
                red[wave][mi * 16 + quad * 4 + r] = rows[mi * 4 + r];
    }
    __syncthreads();
    if (tid < 128) {
        int wmv = tid >> 6, ml = tid & 63;
        float sum = red[wmv * 2][ml] + red[wmv * 2 + 1][ml];
        etp[(size_t)nt * (1024 * 128) + (size_t)mt * 128 + tid] = sum;
    }
}

// ---------------------------------------------------------------------------
// K3: softmax over T per batch; sums the 4 etp N-partials inline. grid 64 x 256
__global__ __launch_bounds__(256) void k_softmax(const float* __restrict__ etp,
                                                 float* __restrict__ at) {
    __shared__ float sred[256];
    int b = blockIdx.x;
    const float* e = etp + b * T;
    float vals[8];
    float mx = -1e30f;
#pragma unroll
    for (int i = 0; i < 8; ++i) {
        int t = threadIdx.x + i * 256;
        float x = e[t] + e[131072 + t] + e[2 * 131072 + t] + e[3 * 131072 + t];
        vals[i] = x;
        mx = fmaxf(mx, x);
    }
    sred[threadIdx.x] = mx;
    __syncthreads();
    for (int s = 128; s > 0; s >>= 1) {
        if (threadIdx.x < s) sred[threadIdx.x] = fmaxf(sred[threadIdx.x], sred[threadIdx.x + s]);
        __syncthreads();
    }
    mx = sred[0];
    __syncthreads();
    float sum = 0.f;
#pragma unroll
    for (int i = 0; i < 8; ++i) {
        float x = exp2f((vals[i] - mx) * 1.4426950408889634f);
        vals[i] = x;
        sum += x;
    }
    sred[threadIdx.x] = sum;
    __syncthreads();
    for (int s = 128; s > 0; s >>= 1) {
        if (threadIdx.x < s) sred[threadIdx.x] += sred[threadIdx.x + s];
        __syncthreads();
    }
    float inv = 1.0f / sred[0];
#pragma unroll
    for (int i = 0; i < 8; ++i) at[b * T + threadIdx.x + i * 256] = vals[i] * inv;
}

// ---------------------------------------------------------------------------
// K4: context partials. grid (64*16) x 256
__global__ __launch_bounds__(256) void k_ctx_part(const float* __restrict__ at,
                                                  const float* __restrict__ ann,
                                                  float* __restrict__ part) {
    int b = blockIdx.x >> 4;
    int tc = blockIdx.x & 15;
    int a2 = threadIdx.x << 1;
    const float* annb = ann + ((size_t)b * T + tc * 128) * A;
    const float* atb = at + b * T + tc * 128;
    float acc0 = 0.f, acc1 = 0.f;
    for (int t = 0; t < 128; ++t) {
        float w = atb[t];
        float2 rv = *(const float2*)(annb + (size_t)t * A + a2);
        acc0 += w * rv.x;
        acc1 += w * rv.y;
    }
    float* p = part + ((size_t)b * 16 + tc) * A;
    p[a2] = acc0;
    p[a2 + 1] = acc1;
}

// ---------------------------------------------------------------------------
// K5: reduce partials -> context. grid 64 x 256
__global__ __launch_bounds__(256) void k_ctx_reduce(const float* __restrict__ part,
                                                    float* __restrict__ ctx) {
    int b = blockIdx.x;
    for (int a = threadIdx.x; a < A; a += 256) {
        float s = 0.f;
#pragma unroll
        for (int c = 0; c < 16; ++c) s += part[((size_t)b * 16 + c) * A + a];
        ctx[b * A + a] = s;
    }
}

// ---------------------------------------------------------------------------
// K5b: xb[b][0:1536] = bf16([inputs | ctx | h]). grid (6, 64) x 256
__global__ __launch_bounds__(256) void k_prep_xb(const float* __restrict__ inputs,
                                                 const float* __restrict__ ctx,
                                                 const float* __restrict__ h,
                                                 unsigned short* __restrict__ xb) {
    int b = blockIdx.y;
    int k = blockIdx.x * 256 + threadIdx.x;
    float val;
    if (k < 512) val = inputs[b * 512 + k];
    else if (k < 1024) val = ctx[b * 512 + (k - 512)];
    else val = h[b * 512 + (k - 1024)];
    xb[b * 1536 + k] = f32_to_bf16(val);
}

// ---------------------------------------------------------------------------
// K6a: z-GEMM, split-K MFMA. grid 256 x 256.
__global__ __launch_bounds__(256) void k_zgemm(const unsigned short* __restrict__ xb,
                                               const unsigned short* __restrict__ Wt,
                                               float* __restrict__ zpart) {
    const int kc = blockIdx.x & 7;
    const int nt = blockIdx.x >> 3;
    const int wave = threadIdx.x >> 6;
    const int lane = threadIdx.x & 63;
    const int lanelo = lane & 15;
    const int quad = lane >> 4;

    const int n = nt * 64 + wave * 16 + lanelo;
    const unsigned short* bp = Wt + (size_t)n * 1536 + kc * 192 + quad * 8;
    const unsigned short* ap = xb + (size_t)lanelo * 1536 + kc * 192 + quad * 8;

    f32x4 acc[4];
#pragma unroll
    for (int i = 0; i < 4; ++i) acc[i] = {0.f, 0.f, 0.f, 0.f};

#pragma unroll
    for (int ks = 0; ks < 6; ++ks) {
        short8 bfrag = *(const short8*)(bp + ks * 32);
#pragma unroll
        for (int mi = 0; mi < 4; ++mi) {
            short8 afrag = *(const short8*)(ap + (size_t)mi * 16 * 1536 + ks * 32);
            acc[mi] = __builtin_amdgcn_mfma_f32_16x16x32_bf16(afrag, bfrag, acc[mi], 0, 0, 0);
        }
    }

    float* p = zpart + (size_t)kc * 64 * 2048;
#pragma unroll
    for (int mi = 0; mi < 4; ++mi)
#pragma unroll
        for (int r = 0; r < 4; ++r) {
            int m = mi * 16 + quad * 4 + r;
            p[(size_t)m * 2048 + n] = acc[mi][r];
        }
}

// ---------------------------------------------------------------------------
// K6b: combine partials + bias -> gates -> h_new. grid 128 x 256
__global__ __launch_bounds__(256) void k_gates(const float* __restrict__ zpart,
                                               const float* __restrict__ bias,
                                               const float* __restrict__ c,
                                               float* __restrict__ hnew) {
    int gid = blockIdx.x * 256 + threadIdx.x;
    int b = gid >> 9;
    int u = gid & 511;
    float z[4];
#pragma unroll
    for (int g = 0; g < 4; ++g) {
        int j = (g << 9) + u;
        float s = bias[j];
#pragma unroll
        for (int kc = 0; kc < 8; ++kc)
            s += zpart[((size_t)kc * 64 + b) * 2048 + j];
        z[g] = s;
    }
    float ig = hard_sigmoid(z[0]);
    float fg = hard_sigmoid(z[1]);
    float cn = fg * c[b * 512 + u] + ig * fast_tanh(z[2]);
    float og = hard_sigmoid(z[3]);
    hnew[b * 512 + u] = og * fast_tanh(cn);
}

// ---------------------------------------------------------------------------
extern "C" void kernel_launch(void* const* d_in, const int* in_sizes, int n_in,
                              void* d_out, int out_size, void* d_ws, size_t ws_size,
                              hipStream_t stream) {
    const float* inputs = (const float*)d_in[0];
    const float* h      = (const float*)d_in[1];
    const float* c      = (const float*)d_in[2];
    const float* ann    = (const float*)d_in[3];
    const float* kern   = (const float*)d_in[4];
    const float* rk     = (const float*)d_in[5];
    const float* bias   = (const float*)d_in[6];
    const float* ku     = (const float*)d_in[7];
    const float* kw     = (const float*)d_in[8];
    const float* kv     = (const float*)d_in[9];

    // ws layout (bytes):
    //   S      @ 0         131072
    //   kut    @ 131072    524288
    //   etp    @ 655360    2097152   (4 N-partials x 131072 fp32)
    //   at     @ 2752512   524288
    //   part   @ 3276800   2097152   (ctx partials; also Sp early, 524288)
    //   ctx    @ 5373952   131072
    //   xb     @ 5505024   196608
    //   Wt     @ 5701632   6291456
    //   zpart  @ 11993088  4194304
    char* ws = (char*)d_ws;
    float*          S     = (float*)(ws + 0);
    unsigned short* kut   = (unsigned short*)(ws + 131072);
    float*          etp   = (float*)(ws + 655360);
    float*          at    = (float*)(ws + 2752512);
    float*          part  = (float*)(ws + 3276800);
    float*          Sp    = (float*)(ws + 3276800);   // alias: consumed before part written
    float*          ctx   = (float*)(ws + 5373952);
    unsigned short* xb    = (unsigned short*)(ws + 5505024);
    unsigned short* Wt    = (unsigned short*)(ws + 5701632);
    float*          zpart = (float*)(ws + 11993088);
    float*          hnew  = (float*)d_out;

    k_prep_wt<<<dim3(48, 64), 256, 0, stream>>>(kern, rk, Wt);
    k_prep_kut<<<256, 256, 0, stream>>>(ku, kut);
    k_prep_s<<<256, 256, 0, stream>>>(h, kw, Sp);
    k_s_reduce<<<128, 256, 0, stream>>>(Sp, bias, S);
    k_gemm_et<<<4096, 256, 0, stream>>>(ann, kut, S, kv, etp);
    k_softmax<<<64, 256, 0, stream>>>(etp, at);
    k_ctx_part<<<64 * 16, 256, 0, stream>>>(at, ann, part);
    k_ctx_reduce<<<64, 256, 0, stream>>>(part, ctx);
    k_prep_xb<<<dim3(6, 64), 256, 0, stream>>>(inputs, ctx, h, xb);
    k_zgemm<<<256, 256, 0, stream>>>(xb, Wt, zpart);
    k_gates<<<128, 256, 0, stream>>>(zpart, bias, c, hnew);
}

// Round 4
// 516.688 us; speedup vs baseline: 1.9752x; 1.0789x over previous
//
#include <hip/hip_runtime.h>

// Problem constants (B,T,A,D,U) = (64, 2048, 512, 512, 512)
constexpr int U = 512;
constexpr int B = 64;
constexpr int T = 2048;
constexpr int A = 512;

typedef __attribute__((ext_vector_type(8))) short short8;   // 8 bf16 = 4 VGPRs (MFMA A/B frag)
typedef __attribute__((ext_vector_type(4))) float f32x4;    // MFMA C/D frag

__device__ __forceinline__ unsigned short f32_to_bf16(float f) {
    unsigned int b = __float_as_uint(f);
    unsigned int r = (b + 0x7FFFu + ((b >> 16) & 1u)) >> 16;
    return (unsigned short)r;
}

__device__ __forceinline__ float fast_tanh(float x) {
    float e = exp2f(x * 2.885390081777927f);
    return (e - 1.0f) * __builtin_amdgcn_rcpf(e + 1.0f);
}

__device__ __forceinline__ float hard_sigmoid(float z) {
    return fminf(fmaxf(0.2f * z + 0.5f, 0.0f), 1.0f);
}

// ---------------------------------------------------------------------------
// K1a: split-K partials for S = bias_u + h @ kernel_w. grid 256 x 256.
__global__ __launch_bounds__(256) void k_prep_s(const float* __restrict__ h,
                                                const float* __restrict__ kw,
                                                float* __restrict__ Sp) {
    int b = blockIdx.x >> 2;
    int kc = blockIdx.x & 3;
    int u = threadIdx.x;
    const float* hb = h + b * U + kc * 128;
    const float* kwb = kw + (size_t)kc * 128 * U;
    float a0 = 0.f, a1 = 0.f;
#pragma unroll 4
    for (int k = 0; k < 128; ++k) {
        float hv = hb[k];
        a0 += hv * kwb[(size_t)k * U + u];
        a1 += hv * kwb[(size_t)k * U + u + 256];
    }
    float* p = Sp + ((size_t)kc * 64 + b) * U;
    p[u] = a0;
    p[u + 256] = a1;
}

// K1a2: S[b][u] = bias_u[u] + sum_kc Sp. grid 128 x 256
__global__ __launch_bounds__(256) void k_s_reduce(const float* __restrict__ Sp,
                                                  const float* __restrict__ bias,
                                                  float* __restrict__ S) {
    int gid = blockIdx.x * 256 + threadIdx.x;
    int b = gid >> 9, u = gid & 511;
    float s = bias[4 * U + u];
#pragma unroll
    for (int kc = 0; kc < 4; ++kc) s += Sp[((size_t)kc * 64 + b) * U + u];
    S[gid] = s;
}

// ---------------------------------------------------------------------------
// K1b: kut[u][a] = bf16(kernel_u[a][u]). grid 256 x 256
__global__ __launch_bounds__(256) void k_prep_kut(const float* __restrict__ ku,
                                                  unsigned short* __restrict__ kut) {
    __shared__ float tile[32][33];
    int a0 = (blockIdx.x >> 4) << 5;
    int u0 = (blockIdx.x & 15) << 5;
    int c = threadIdx.x & 31, r0 = threadIdx.x >> 5;
#pragma unroll
    for (int p = 0; p < 4; ++p) {
        int r = r0 + p * 8;
        tile[r][c] = ku[(a0 + r) * U + u0 + c];
    }
    __syncthreads();
#pragma unroll
    for (int p = 0; p < 4; ++p) {
        int r = r0 + p * 8;
        kut[(u0 + r) * A + a0 + c] = f32_to_bf16(tile[c][r]);
    }
}

// ---------------------------------------------------------------------------
// K1c: Wt[j][k] = bf16( W[k][j] ). grid (48, 64) x 256
__global__ __launch_bounds__(256) void k_prep_wt(const float* __restrict__ kern,
                                                 const float* __restrict__ rk,
                                                 unsigned short* __restrict__ Wt) {
    __shared__ float tile[32][33];
    int k0 = blockIdx.x << 5;
    int j0 = blockIdx.y << 5;
    int c = threadIdx.x & 31, r0 = threadIdx.x >> 5;
#pragma unroll
    for (int p = 0; p < 4; ++p) {
        int r = r0 + p * 8;
        int k = k0 + r;
        float val = (k < 1024) ? kern[k * 2048 + j0 + c]
                               : rk[(k - 1024) * 2048 + j0 + c];
        tile[r][c] = val;
    }
    __syncthreads();
#pragma unroll
    for (int p = 0; p < 4; ++p) {
        int r = r0 + p * 8;
        Wt[(size_t)(j0 + r) * 1536 + k0 + c] = f32_to_bf16(tile[c][r]);
    }
}

// ---------------------------------------------------------------------------
// K2: 128(M) x 256(N) MFMA GEMM + fused tanh/dot(v) epilogue.
//   uh = ann @ ku (bf16), etp[nt][m] = sum_{u in nt half} tanh(uh+S)*v[u]
// 256 thr = 4 waves in 2(M)x2(N); wave-tile 64x128 (acc 4x8) -> 64 MFMA per
// wave per BK=64 iter. A: fp32->bf16->ds_write, B: global_load_lds w=16.
// Both LDS tiles unpadded, XOR-chunk swizzle (chunk c of row r at slot
// c^(r&7)) -> conflict-free b128 reads. Grid decode pairs the two nt-siblings
// of each mt onto the SAME XCD (bid%8 equal, dispatched 8 apart) so the
// second fp32 A-tile read hits that XCD's L2, not HBM.
// grid 2048 x 256.
__global__ __launch_bounds__(256, 2) void k_gemm_et(const float* __restrict__ ann,
                                                    const unsigned short* __restrict__ kut,
                                                    const float* __restrict__ S,
                                                    const float* __restrict__ v,
                                                    float* __restrict__ etp) {
    __shared__ unsigned short As[128 * 64];   // 16 KB, swizzled
    __shared__ unsigned short Bs[256 * 64];   // 32 KB, swizzled (gll target)
    __shared__ float red[4][64];

    const int tid = threadIdx.x;
    const int wave = tid >> 6;
    const int lane = tid & 63;
    const int lanelo = lane & 15;
    const int quad = lane >> 4;
    const int wm = wave >> 1, wn = wave & 1;

    const int bid = blockIdx.x;
    const int nt = (bid >> 3) & 1;
    const int mt = (bid & 7) | ((bid >> 4) << 3);   // 0..1023
    const int b = mt >> 4;                          // 16 m-tiles per batch
    const float* aBase = ann + (size_t)mt * 128 * A;
    const unsigned short* bBase = kut + (size_t)nt * 256 * A;

    f32x4 acc[4][8];
#pragma unroll
    for (int i = 0; i < 4; ++i)
#pragma unroll
        for (int j = 0; j < 8; ++j) acc[i][j] = {0.f, 0.f, 0.f, 0.f};

    for (int k0 = 0; k0 < A; k0 += 64) {
        // --- B staging: 32 KB via async global->LDS, 8 issues/wave ---
#pragma unroll
        for (int p = 0; p < 8; ++p) {
            int seg = p * 4 + wave;                   // 1 KB segment
            int flat = seg * 1024 + lane * 16;        // byte offset in Bs
            int row = flat >> 7;                      // n-local 0..255
            int sc = (flat >> 4) & 7;                 // stored chunk slot
            int d = sc ^ (row & 7);                   // global chunk fetched
            __builtin_amdgcn_global_load_lds(
                (const __attribute__((address_space(1))) void*)(bBase + (size_t)row * A + k0 + d * 8),
                (__attribute__((address_space(3))) void*)((char*)Bs + seg * 1024),
                16, 0, 0);
        }
        // --- A staging: fp32 load, convert, swizzled 16B LDS store ---
#pragma unroll
        for (int p = 0; p < 4; ++p) {
            int flat8 = p * 256 + tid;         // 8-float chunk (0..1023)
            int row = flat8 >> 3;              // 0..127
            int c8 = flat8 & 7;
            const float* src = aBase + (size_t)row * A + k0 + c8 * 8;
            f32x4 v0 = *(const f32x4*)src;
            f32x4 v1 = *(const f32x4*)(src + 4);
            short8 pk;
            pk[0] = (short)f32_to_bf16(v0.x);
            pk[1] = (short)f32_to_bf16(v0.y);
            pk[2] = (short)f32_to_bf16(v0.z);
            pk[3] = (short)f32_to_bf16(v0.w);
            pk[4] = (short)f32_to_bf16(v1.x);
            pk[5] = (short)f32_to_bf16(v1.y);
            pk[6] = (short)f32_to_bf16(v1.z);
            pk[7] = (short)f32_to_bf16(v1.w);
            *(short8*)&As[row * 64 + ((c8 ^ (row & 7)) * 8)] = pk;
        }
        __syncthreads();
        // --- inner: 2 K=32 steps, 64 MFMA/wave per iter ---
#pragma unroll
        for (int s = 0; s < 2; ++s) {
            int c = s * 4 + quad;
            short8 af[4];
#pragma unroll
            for (int mi = 0; mi < 4; ++mi) {
                int row = wm * 64 + mi * 16 + lanelo;
                af[mi] = *(const short8*)&As[row * 64 + ((c ^ (row & 7)) * 8)];
            }
            short8 bfr[8];
#pragma unroll
            for (int ni = 0; ni < 8; ++ni) {
                int rowb = wn * 128 + ni * 16 + lanelo;
                bfr[ni] = *(const short8*)&Bs[rowb * 64 + ((c ^ (rowb & 7)) * 8)];
            }
#pragma unroll
            for (int mi = 0; mi < 4; ++mi)
#pragma unroll
                for (int ni = 0; ni < 8; ++ni)
                    acc[mi][ni] = __builtin_amdgcn_mfma_f32_16x16x32_bf16(
                        af[mi], bfr[ni], acc[mi][ni], 0, 0, 0);
        }
        __syncthreads();
    }

    // Epilogue. C/D: col(n) = lane&15, row(m) = quad*4 + r (verified m89/m91).
    float rows[16];
#pragma unroll
    for (int i = 0; i < 16; ++i) rows[i] = 0.f;
#pragma unroll
    for (int ni = 0; ni < 8; ++ni) {
        int n = nt * 256 + wn * 128 + ni * 16 + lanelo;
        float sv = S[b * U + n];
        float vv = v[n];
#pragma unroll
        for (int mi = 0; mi < 4; ++mi)
#pragma unroll
            for (int r = 0; r < 4; ++r)
                rows[mi * 4 + r] += fast_tanh(acc[mi][ni][r] + sv) * vv;
    }
#pragma unroll
    for (int i = 0; i < 16; ++i) {
        rows[i] += __shfl_xor(rows[i], 1);
        rows[i] += __shfl_xor(rows[i], 2);
        rows[i] += __shfl_xor(rows[i], 4);
        rows[i] += __shfl_xor(rows[i], 8);
    }
    if (lanelo == 0) {
#pragma unroll
        for (int mi = 0; mi < 4; ++mi)
#pragma unroll
            for (int r = 0; r < 4; ++r)
                red[wave][mi * 16 + quad * 4 + r] = rows[mi * 4 + r];
    }
    __syncthreads();
    if (tid < 128) {
        int wmv = tid >> 6, ml = tid & 63;
        float sum = red[wmv * 2][ml] + red[wmv * 2 + 1][ml];
        etp[(size_t)nt * (1024 * 128) + (size_t)mt * 128 + tid] = sum;
    }
}

// ---------------------------------------------------------------------------
// K3: softmax over T per batch; sums the 2 etp N-partials inline. grid 64 x 256
__global__ __launch_bounds__(256) void k_softmax(const float* __restrict__ etp,
                                                 float* __restrict__ at) {
    __shared__ float sred[256];
    int b = blockIdx.x;
    const float* e = etp + b * T;
    float vals[8];
    float mx = -1e30f;
#pragma unroll
    for (int i = 0; i < 8; ++i) {
        int t = threadIdx.x + i * 256;
        float x = e[t] + e[131072 + t];
        vals[i] = x;
        mx = fmaxf(mx, x);
    }
    sred[threadIdx.x] = mx;
    __syncthreads();
    for (int s = 128; s > 0; s >>= 1) {
        if (threadIdx.x < s) sred[threadIdx.x] = fmaxf(sred[threadIdx.x], sred[threadIdx.x + s]);
        __syncthreads();
    }
    mx = sred[0];
    __syncthreads();
    float sum = 0.f;
#pragma unroll
    for (int i = 0; i < 8; ++i) {
        float x = exp2f((vals[i] - mx) * 1.4426950408889634f);
        vals[i] = x;
        sum += x;
    }
    sred[threadIdx.x] = sum;
    __syncthreads();
    for (int s = 128; s > 0; s >>= 1) {
        if (threadIdx.x < s) sred[threadIdx.x] += sred[threadIdx.x + s];
        __syncthreads();
    }
    float inv = 1.0f / sred[0];
#pragma unroll
    for (int i = 0; i < 8; ++i) at[b * T + threadIdx.x + i * 256] = vals[i] * inv;
}

// ---------------------------------------------------------------------------
// K4: context partials, 16 B/lane. t-chunks of 256, two t's in flight
// (half-waves), LDS combine. grid (64*8) x 256.
__global__ __launch_bounds__(256) void k_ctx_part(const float* __restrict__ at,
                                                  const float* __restrict__ ann,
                                                  float* __restrict__ part) {
    __shared__ float buf[2][512];
    int b = blockIdx.x >> 3;
    int tc = blockIdx.x & 7;
    int half = threadIdx.x >> 7;        // 0..1
    int a4 = (threadIdx.x & 127) << 2;  // 0,4,...,508
    const float* annb = ann + ((size_t)b * T + tc * 256) * A;
    const float* atb = at + b * T + tc * 256;
    f32x4 acc = {0.f, 0.f, 0.f, 0.f};
    for (int t = half; t < 256; t += 2) {
        float w = atb[t];
        f32x4 rv = *(const f32x4*)(annb + (size_t)t * A + a4);
        acc.x += w * rv.x;
        acc.y += w * rv.y;
        acc.z += w * rv.z;
        acc.w += w * rv.w;
    }
    *(f32x4*)&buf[half][a4] = acc;
    __syncthreads();
    int a2 = threadIdx.x << 1;
    float s0 = buf[0][a2] + buf[1][a2];
    float s1 = buf[0][a2 + 1] + buf[1][a2 + 1];
    float* p = part + ((size_t)b * 8 + tc) * A;
    p[a2] = s0;
    p[a2 + 1] = s1;
}

// ---------------------------------------------------------------------------
// K5: reduce partials -> context. grid 64 x 256
__global__ __launch_bounds__(256) void k_ctx_reduce(const float* __restrict__ part,
                                                    float* __restrict__ ctx) {
    int b = blockIdx.x;
    for (int a = threadIdx.x; a < A; a += 256) {
        float s = 0.f;
#pragma unroll
        for (int c = 0; c < 8; ++c) s += part[((size_t)b * 8 + c) * A + a];
        ctx[b * A + a] = s;
    }
}

// ---------------------------------------------------------------------------
// K5b: xb[b][0:1536] = bf16([inputs | ctx | h]). grid (6, 64) x 256
__global__ __launch_bounds__(256) void k_prep_xb(const float* __restrict__ inputs,
                                                 const float* __restrict__ ctx,
                                                 const float* __restrict__ h,
                                                 unsigned short* __restrict__ xb) {
    int b = blockIdx.y;
    int k = blockIdx.x * 256 + threadIdx.x;
    float val;
    if (k < 512) val = inputs[b * 512 + k];
    else if (k < 1024) val = ctx[b * 512 + (k - 512)];
    else val = h[b * 512 + (k - 1024)];
    xb[b * 1536 + k] = f32_to_bf16(val);
}

// ---------------------------------------------------------------------------
// K6a: z-GEMM, split-K MFMA. grid 256 x 256.
__global__ __launch_bounds__(256) void k_zgemm(const unsigned short* __restrict__ xb,
                                               const unsigned short* __restrict__ Wt,
                                               float* __restrict__ zpart) {
    const int kc = blockIdx.x & 7;
    const int nt = blockIdx.x >> 3;
    const int wave = threadIdx.x >> 6;
    const int lane = threadIdx.x & 63;
    const int lanelo = lane & 15;
    const int quad = lane >> 4;

    const int n = nt * 64 + wave * 16 + lanelo;
    const unsigned short* bp = Wt + (size_t)n * 1536 + kc * 192 + quad * 8;
    const unsigned short* ap = xb + (size_t)lanelo * 1536 + kc * 192 + quad * 8;

    f32x4 acc[4];
#pragma unroll
    for (int i = 0; i < 4; ++i) acc[i] = {0.f, 0.f, 0.f, 0.f};

#pragma unroll
    for (int ks = 0; ks < 6; ++ks) {
        short8 bfrag = *(const short8*)(bp + ks * 32);
#pragma unroll
        for (int mi = 0; mi < 4; ++mi) {
            short8 afrag = *(const short8*)(ap + (size_t)mi * 16 * 1536 + ks * 32);
            acc[mi] = __builtin_amdgcn_mfma_f32_16x16x32_bf16(afrag, bfrag, acc[mi], 0, 0, 0);
        }
    }

    float* p = zpart + (size_t)kc * 64 * 2048;
#pragma unroll
    for (int mi = 0; mi < 4; ++mi)
#pragma unroll
        for (int r = 0; r < 4; ++r) {
            int m = mi * 16 + quad * 4 + r;
            p[(size_t)m * 2048 + n] = acc[mi][r];
        }
}

// ---------------------------------------------------------------------------
// K6b: combine partials + bias -> gates -> h_new. grid 128 x 256
__global__ __launch_bounds__(256) void k_gates(const float* __restrict__ zpart,
                                               const float* __restrict__ bias,
                                               const float* __restrict__ c,
                                               float* __restrict__ hnew) {
    int gid = blockIdx.x * 256 + threadIdx.x;
    int b = gid >> 9;
    int u = gid & 511;
    float z[4];
#pragma unroll
    for (int g = 0; g < 4; ++g) {
        int j = (g << 9) + u;
        float s = bias[j];
#pragma unroll
        for (int kc = 0; kc < 8; ++kc)
            s += zpart[((size_t)kc * 64 + b) * 2048 + j];
        z[g] = s;
    }
    float ig = hard_sigmoid(z[0]);
    float fg = hard_sigmoid(z[1]);
    float cn = fg * c[b * 512 + u] + ig * fast_tanh(z[2]);
    float og = hard_sigmoid(z[3]);
    hnew[b * 512 + u] = og * fast_tanh(cn);
}

// ---------------------------------------------------------------------------
extern "C" void kernel_launch(void* const* d_in, const int* in_sizes, int n_in,
                              void* d_out, int out_size, void* d_ws, size_t ws_size,
                              hipStream_t stream) {
    const float* inputs = (const float*)d_in[0];
    const float* h      = (const float*)d_in[1];
    const float* c      = (const float*)d_in[2];
    const float* ann    = (const float*)d_in[3];
    const float* kern   = (const float*)d_in[4];
    const float* rk     = (const float*)d_in[5];
    const float* bias   = (const float*)d_in[6];
    const float* ku     = (const float*)d_in[7];
    const float* kw     = (const float*)d_in[8];
    const float* kv     = (const float*)d_in[9];

    // ws layout (bytes):
    //   S      @ 0         131072
    //   kut    @ 131072    524288
    //   etp    @ 655360    1048576   (2 N-partials x 131072 fp32)
    //   at     @ 1703936   524288
    //   part   @ 2228224   1048576   (ctx partials, 8 chunks; Sp alias early)
    //   ctx    @ 3276800   131072
    //   xb     @ 3407872   196608
    //   Wt     @ 3604480   6291456
    //   zpart  @ 9895936   4194304
    char* ws = (char*)d_ws;
    float*          S     = (float*)(ws + 0);
    unsigned short* kut   = (unsigned short*)(ws + 131072);
    float*          etp   = (float*)(ws + 655360);
    float*          at    = (float*)(ws + 1703936);
    float*          part  = (float*)(ws + 2228224);
    float*          Sp    = (float*)(ws + 2228224);   // alias: consumed before part written
    float*          ctx   = (float*)(ws + 3276800);
    unsigned short* xb    = (unsigned short*)(ws + 3407872);
    unsigned short* Wt    = (unsigned short*)(ws + 3604480);
    float*          zpart = (float*)(ws + 9895936);
    float*          hnew  = (float*)d_out;

    k_prep_wt<<<dim3(48, 64), 256, 0, stream>>>(kern, rk, Wt);
    k_prep_kut<<<256, 256, 0, stream>>>(ku, kut);
    k_prep_s<<<256, 256, 0, stream>>>(h, kw, Sp);
    k_s_reduce<<<128, 256, 0, stream>>>(Sp, bias, S);
    k_gemm_et<<<2048, 256, 0, stream>>>(ann, kut, S, kv, etp);
    k_softmax<<<64, 256, 0, stream>>>(etp, at);
    k_ctx_part<<<64 * 8, 256, 0, stream>>>(at, ann, part);
    k_ctx_reduce<<<64, 256, 0, stream>>>(part, ctx);
    k_prep_xb<<<dim3(6, 64), 256, 0, stream>>>(inputs, ctx, h, xb);
    k_zgemm<<<256, 256, 0, stream>>>(xb, Wt, zpart);
    k_gates<<<128, 256, 0, stream>>>(zpart, bias, c, hnew);
}